// Round 1
// baseline (48.216 us; speedup 1.0000x reference)
//
#include <hip/hip_runtime.h>

// Problem constants (fixed by the reference).
constexpr int T = 1024;   // frames
constexpr int B = 32;     // batch
constexpr int D = 512;    // feature dim
constexpr int C = 1024;   // classes
constexpr int BLANK = 0;

// ---------------------------------------------------------------------------
// Kernel 1: per-(t,b) argmax over C logits. One wave (64 lanes) per row.
// Row layout: logit[t, b, c] contiguous in c -> row base = (t*B + b) * C.
// Tie-break: first occurrence (lowest index), matching jnp.argmax.
// pred written as [B, T] with padding applied.
// ---------------------------------------------------------------------------
__global__ __launch_bounds__(256) void argmax_kernel(
    const float* __restrict__ logit,
    const unsigned char* __restrict__ padding,   // [B, T] (all zeros in setup)
    int* __restrict__ pred)                      // [B, T]
{
    const int lane = threadIdx.x & 63;
    const int wid  = threadIdx.x >> 6;
    const int row  = blockIdx.x * 4 + wid;       // row = t*B + b, < T*B
    const int t = row / B;
    const int b = row - t * B;

    const float4* lp = (const float4*)(logit + (size_t)row * C);
    float bv = -3.4e38f;
    int   bi = 0;
    #pragma unroll
    for (int k = 0; k < 4; ++k) {
        float4 v = lp[lane + 64 * k];
        const int c0 = 4 * (lane + 64 * k);      // ascending in k for fixed lane
        if (v.x > bv) { bv = v.x; bi = c0;     }
        if (v.y > bv) { bv = v.y; bi = c0 + 1; }
        if (v.z > bv) { bv = v.z; bi = c0 + 2; }
        if (v.w > bv) { bv = v.w; bi = c0 + 3; }
    }
    #pragma unroll
    for (int off = 32; off; off >>= 1) {
        float ov = __shfl_xor(bv, off);
        int   oi = __shfl_xor(bi, off);
        if (ov > bv || (ov == bv && oi < bi)) { bv = ov; bi = oi; }
    }
    if (lane == 0) {
        pred[b * T + t] = padding[b * T + t] ? BLANK : bi;
    }
}

// ---------------------------------------------------------------------------
// Kernel 2: per-batch compaction + run-length grouping. One 1024-thread block
// per batch. Ballot/popc prefix sums (wave64).
// Emits: src_t[b][j]   = original t of j-th non-blank frame
//        run_start[b][n] (compacted index where run n begins; [new_len]=M)
//        new_len[b]
// and writes the cheap outputs directly: out_padding (0/1 f32), gloss (f32),
// new_len (f32).
// ---------------------------------------------------------------------------
__global__ __launch_bounds__(1024) void runs_kernel(
    const int* __restrict__ pred,         // [B, T]
    int* __restrict__ src_t,              // [B, T]
    int* __restrict__ run_start,          // [B, T+1]
    int* __restrict__ new_len_ws,         // [B]
    float* __restrict__ pad_f,            // [B, T]  out_padding as float
    float* __restrict__ gloss_f,          // [B, T]  gloss_fake as float
    float* __restrict__ newlen_f)         // [B]     new_len as float
{
    __shared__ int cp_s[T];
    __shared__ int srct_s[T];
    __shared__ int run_start_s[T + 1];
    __shared__ int wsum[17];
    __shared__ int wsum2[17];

    const int b    = blockIdx.x;
    const int t    = threadIdx.x;
    const int lane = t & 63;
    const int wid  = t >> 6;

    cp_s[t]   = -1;
    srct_s[t] = 0;

    // --- phase 1: compact non-blank frames ---
    const int  p = pred[b * T + t];
    const bool m = (p != BLANK);
    unsigned long long bal = __ballot(m);
    const int pre = __popcll(bal & ((1ull << lane) - 1ull));
    if (lane == 0) wsum[wid] = __popcll(bal);
    __syncthreads();                                  // (A)
    if (t == 0) {
        int r = 0;
        for (int i = 0; i < 16; ++i) { int v = wsum[i]; wsum[i] = r; r += v; }
        wsum[16] = r;
    }
    __syncthreads();                                  // (B)
    const int M = wsum[16];
    if (m) {
        const int d = wsum[wid] + pre;
        cp_s[d]   = p;
        srct_s[d] = t;
    }
    run_start_s[t] = M;
    if (t == 0) run_start_s[T] = M;
    __syncthreads();                                  // (C)

    // --- phase 2: run starts on the compacted sequence ---
    const int  c     = cp_s[t];
    const bool valid = (t < M);
    const bool start = valid && (t == 0 || c != cp_s[t - 1]);
    unsigned long long bal2 = __ballot(start);
    const int pre2 = __popcll(bal2 & ((1ull << lane) - 1ull));
    if (lane == 0) wsum2[wid] = __popcll(bal2);
    __syncthreads();                                  // (D)
    if (t == 0) {
        int r = 0;
        for (int i = 0; i < 16; ++i) { int v = wsum2[i]; wsum2[i] = r; r += v; }
        wsum2[16] = r;
    }
    __syncthreads();                                  // (E)
    const int NL = wsum2[16];
    if (start) run_start_s[wsum2[wid] + pre2] = t;    // indices < NL only;
                                                      // [NL..T] stay == M
    __syncthreads();                                  // (F)

    // --- outputs ---
    src_t[b * T + t]           = srct_s[t];
    run_start[b * (T + 1) + t] = run_start_s[t];
    if (t == 0) run_start[b * (T + 1) + T] = run_start_s[T];

    pad_f[b * T + t] = (t >= NL) ? 1.0f : 0.0f;
    const int g = (t < NL) ? cp_s[run_start_s[t]] : -1;
    gloss_f[b * T + t] = (float)g;

    if (t == 0) {
        new_len_ws[b] = NL;
        newlen_f[b]   = (float)NL;
    }
}

// ---------------------------------------------------------------------------
// Kernel 3: per-run mean of representation rows. One wave per (n, b) output
// row. out[n, b, :] = mean_{j in run n} rep[src_t[j], b, :]; zeros for
// n >= new_len. D=512 -> 2 float4 per lane.
// ---------------------------------------------------------------------------
__global__ __launch_bounds__(64) void avg_kernel(
    const float* __restrict__ rep,          // [T, B, D]
    const int* __restrict__ src_t,          // [B, T]
    const int* __restrict__ run_start,      // [B, T+1]
    const int* __restrict__ new_len_ws,     // [B]
    float* __restrict__ out)                // [T, B, D]
{
    const int n    = blockIdx.x;
    const int b    = blockIdx.y;
    const int lane = threadIdx.x;
    const int NL   = new_len_ws[b];

    float4 a0 = make_float4(0.f, 0.f, 0.f, 0.f);
    float4 a1 = make_float4(0.f, 0.f, 0.f, 0.f);

    if (n < NL) {
        const int s = run_start[b * (T + 1) + n];
        const int e = run_start[b * (T + 1) + n + 1];
        for (int j = s; j < e; ++j) {
            const int t = src_t[b * T + j];
            const float4* row = (const float4*)(rep + ((size_t)t * B + b) * D);
            const float4 v0 = row[lane];
            const float4 v1 = row[lane + 64];
            a0.x += v0.x; a0.y += v0.y; a0.z += v0.z; a0.w += v0.w;
            a1.x += v1.x; a1.y += v1.y; a1.z += v1.z; a1.w += v1.w;
        }
        const float sc = 1.0f / (float)(e - s);
        a0.x *= sc; a0.y *= sc; a0.z *= sc; a0.w *= sc;
        a1.x *= sc; a1.y *= sc; a1.z *= sc; a1.w *= sc;
    }

    float4* orow = (float4*)(out + ((size_t)n * B + b) * D);
    orow[lane]      = a0;
    orow[lane + 64] = a1;
}

// ---------------------------------------------------------------------------
extern "C" void kernel_launch(void* const* d_in, const int* in_sizes, int n_in,
                              void* d_out, int out_size, void* d_ws, size_t ws_size,
                              hipStream_t stream)
{
    const float* rep           = (const float*)d_in[0];   // [T, B, D] f32
    const float* logit         = (const float*)d_in[1];   // [T, B, C] f32
    const unsigned char* padng = (const unsigned char*)d_in[2]; // [B, T] bool

    float* out_f    = (float*)d_out;                       // [T, B, D]
    float* pad_f    = out_f + (size_t)T * B * D;           // [B, T]
    float* gloss_f  = pad_f + (size_t)B * T;               // [B, T]
    float* newlen_f = gloss_f + (size_t)B * T;             // [B]

    char* ws = (char*)d_ws;
    int* pred       = (int*)(ws);                          // B*T ints
    int* src_t      = (int*)(ws + 131072);                 // B*T ints
    int* run_start  = (int*)(ws + 262144);                 // B*(T+1) ints
    int* new_len_ws = (int*)(ws + 262144 + 131200);        // B ints

    argmax_kernel<<<T * B / 4, 256, 0, stream>>>(logit, padng, pred);
    runs_kernel<<<B, 1024, 0, stream>>>(pred, src_t, run_start, new_len_ws,
                                        pad_f, gloss_f, newlen_f);
    avg_kernel<<<dim3(T, B), 64, 0, stream>>>(rep, src_t, run_start,
                                              new_len_ws, out_f);
}